// Round 18
// baseline (198.184 us; speedup 1.0000x reference)
//
#include <hip/hip_runtime.h>
#include <hip/hip_bf16.h>
#include <math.h>

#define N_PROP 600
#define NUM_CLS 151
#define FEAT_DIM 4096
#define K_OUT 100
#define SCORE_THRESH 0.05f
#define NMS_THRESH 0.5f
#define PER_CLS_TOPN 300
#define IMG_W 1024.0f
#define IMG_H 768.0f
#define BBOX_CLIP 4.135166556742356f  /* log(1000/16) */
#define MAXW 10                       /* ceil(600/64) */

// out layout (reference return order, all f32):
#define OF_BOX (K_OUT * FEAT_DIM)      /* 409600: final_boxes [100,4]   */
#define OF_SC  (OF_BOX + K_OUT * 4)    /* 410000: final_scores [100]    */
#define OF_LB  (OF_SC + K_OUT)         /* 410100: final_labels [100]    */
#define OF_VD  (OF_LB + K_OUT)         /* 410200: valid_out [100]       */
#define OF_BPC (OF_VD + K_OUT)         /* 410300: boxes_per_cls [100,151,4] */

// box decode + clip (exact math of the verified R10 decode kernel)
__device__ __forceinline__ float4 decode_box(float4 pb, const float* d) {
  float w = pb.z - pb.x + 1.0f, h = pb.w - pb.y + 1.0f;
  float cx = pb.x + 0.5f * w, cy = pb.y + 0.5f * h;
  float dx = d[0] / 10.0f, dy = d[1] / 10.0f;
  float dw = fminf(d[2] / 5.0f, BBOX_CLIP);
  float dh = fminf(d[3] / 5.0f, BBOX_CLIP);
  float pcx = dx * w + cx, pcy = dy * h + cy;
  float pw = expf(dw) * w, ph = expf(dh) * h;
  float x1 = pcx - 0.5f * pw, y1 = pcy - 0.5f * ph;
  float x2 = pcx + 0.5f * pw - 1.0f, y2 = pcy + 0.5f * ph - 1.0f;
  x1 = fminf(fmaxf(x1, 0.0f), IMG_W - 1.0f);
  y1 = fminf(fmaxf(y1, 0.0f), IMG_H - 1.0f);
  x2 = fminf(fmaxf(x2, 0.0f), IMG_W - 1.0f);
  y2 = fminf(fmaxf(y2, 0.0f), IMG_H - 1.0f);
  return make_float4(x1, y1, x2, y2);
}

// ---------------------------------------------------------------------------
// K1: self-contained per-class greedy NMS.  One block per class 1..150.
// Computes its own row-softmax p[n][j] (thread-serial two-pass) and decodes
// candidate boxes on the fly.  Compact -> bitonic sort -> wave-ballot IoU
// mask -> serial bitmask scan (reference semantics: suppression uses ALL
// keeps; 300-cap masks flags only).  Kept entries fold into packed[n] via
// u64 atomicMax: key = (prob_bits<<32) | ~class (argmax first-max tie-break).
// packed[] must be zeroed beforehand (zero = score 0.0 sentinel).
// ---------------------------------------------------------------------------
__global__ __launch_bounds__(256) void nms_kernel(
    const float* __restrict__ logits, const float* __restrict__ breg,
    const float* __restrict__ pboxes, unsigned long long* __restrict__ packed) {
  int j = blockIdx.x + 1;  // classes 1..150
  int t = threadIdx.x;

  __shared__ int s_m;
  // LDS pool: [0,48000) keys (1024*8B) then IoU mask (600*10*8B);
  // [48000,57600) boxes float4; [57600,58800) idx u16; [58800,59440) keep u8;
  // [59440,61840) prob f32
  alignas(16) __shared__ unsigned char pool[48000 + 9600 + 1280 + 640 + 2400];
  unsigned long long* s_key  = (unsigned long long*)pool;
  unsigned long long* s_mask = (unsigned long long*)pool;
  float4*             s_box  = (float4*)(pool + 48000);
  unsigned short*     s_idx  = (unsigned short*)(pool + 48000 + 9600);
  unsigned char*      s_keep = pool + 48000 + 9600 + 1280;
  float*              s_prob = (float*)(pool + 48000 + 9600 + 1280 + 640);

  if (t == 0) s_m = 0;
  __syncthreads();

  // candidates: softmax over each handled row, threshold on class j
  for (int n = t; n < N_PROP; n += 256) {
    const float* row = logits + (size_t)n * NUM_CLS;
    float mx = -INFINITY;
#pragma unroll 8
    for (int c = 0; c < NUM_CLS; ++c) mx = fmaxf(mx, row[c]);
    float sum = 0.0f;
#pragma unroll 8
    for (int c = 0; c < NUM_CLS; ++c) sum += expf(row[c] - mx);
    float p = expf(row[j] - mx) / sum;
    if (p > SCORE_THRESH) {
      int pos = atomicAdd(&s_m, 1);
      // score desc, index asc when sorted ascending (scores are positive)
      s_key[pos] = ((unsigned long long)(~__float_as_uint(p)) << 32) | (unsigned)n;
    }
  }
  __syncthreads();
  int m = s_m;
  if (m == 0) return;

  int sz = 1;
  while (sz < m) sz <<= 1;
  for (int i = m + t; i < sz; i += 256) s_key[i] = ~0ULL;
  __syncthreads();

  for (int k = 2; k <= sz; k <<= 1) {
    for (int len = k >> 1; len > 0; len >>= 1) {
      for (int i = t; i < sz; i += 256) {
        int p2 = i ^ len;
        if (p2 > i) {
          unsigned long long a = s_key[i], b = s_key[p2];
          bool up = ((i & k) == 0);
          if ((a > b) == up) { s_key[i] = b; s_key[p2] = a; }
        }
      }
      __syncthreads();
    }
  }

  // extract idx/prob + decode sorted boxes on the fly
  for (int i = t; i < m; i += 256) {
    unsigned long long k = s_key[i];
    int n = (int)(k & 0xFFFFFFFFULL);
    s_idx[i] = (unsigned short)n;
    s_prob[i] = __uint_as_float(~(unsigned)(k >> 32));
    float4 pb = *(const float4*)(pboxes + n * 4);
    s_box[i] = decode_box(pb, breg + ((size_t)n * NUM_CLS + j) * 4);
  }
  __syncthreads();  // mask writes may clobber key region after this

  int words = (m + 63) >> 6;
  int wave = t >> 6, lane = t & 63;
  for (int i = wave; i < m; i += 4) {
    float4 bi = s_box[i];
    float ai = (bi.z - bi.x + 1.0f) * (bi.w - bi.y + 1.0f);
    for (int w = 0; w < words; ++w) {
      int jj = (w << 6) + lane;
      bool over = false;
      if (jj < m) {
        float4 bj = s_box[jj];
        float xx1 = fmaxf(bi.x, bj.x), yy1 = fmaxf(bi.y, bj.y);
        float xx2 = fminf(bi.z, bj.z), yy2 = fminf(bi.w, bj.w);
        float iw = fmaxf(xx2 - xx1 + 1.0f, 0.0f);
        float ih = fmaxf(yy2 - yy1 + 1.0f, 0.0f);
        float inter = iw * ih;
        float aj = (bj.z - bj.x + 1.0f) * (bj.w - bj.y + 1.0f);
        over = (inter / (ai + aj - inter)) > NMS_THRESH;
      }
      unsigned long long bal = __ballot(over);
      if (lane == 0) s_mask[(size_t)i * words + w] = bal;
    }
  }
  __syncthreads();

  if (t == 0) {
    unsigned long long removed[MAXW];
    for (int w = 0; w < words; ++w) removed[w] = 0ULL;
    int cnt = 0;
    for (int i = 0; i < m; ++i) {
      if (!((removed[i >> 6] >> (i & 63)) & 1ULL)) {
        ++cnt;
        s_keep[i] = (cnt <= PER_CLS_TOPN) ? 1 : 0;
        const unsigned long long* row = s_mask + (size_t)i * words;
        for (int w = 0; w < words; ++w) removed[w] |= row[w];
      } else {
        s_keep[i] = 0;
      }
    }
  }
  __syncthreads();
  for (int i = t; i < m; i += 256) {
    if (s_keep[i]) {
      unsigned long long key =
          ((unsigned long long)__float_as_uint(s_prob[i]) << 32) |
          (unsigned)(0xFFFFFFFFu - (unsigned)j);
      atomicMax(&packed[s_idx[i]], key);
    }
  }
}

// ---------------------------------------------------------------------------
// K2: fused finalize + gathers.  200 blocks; block b needs rank r of the
// top-100 (r = b or b-100).  Rank-selection over 600 keys replaces the
// bitonic sort: cnt of strictly-smaller keys == ascending position (keys are
// distinct; mapping = value desc, index asc ties — lax.top_k semantics).
// Blocks 0..99: small outputs (rank b) + features row.  100..199: bpc row.
// Boxes are decoded on the fly.  packed[n]==0 => score 0 (sentinel; label/
// boxes masked by mm=0, glab guarded).
// ---------------------------------------------------------------------------
__global__ __launch_bounds__(256) void finalize_gather_kernel(
    const float* __restrict__ features, const float* __restrict__ breg,
    const float* __restrict__ pboxes,
    const unsigned long long* __restrict__ packed, float* __restrict__ out) {
  int b = blockIdx.x;
  int t = threadIdx.x;
  __shared__ unsigned long long s_key[N_PROP];
  __shared__ float s_score[N_PROP];
  __shared__ unsigned s_low[N_PROP];
  __shared__ int s_win;

  for (int n = t; n < N_PROP; n += 256) {
    unsigned long long pk = packed[n];
    float best = __uint_as_float((unsigned)(pk >> 32));
    s_score[n] = best;
    s_low[n] = (unsigned)(pk & 0xFFFFFFFFULL);
    float sel = (best > 0.0f) ? best : -1.0f;
    unsigned int sb = __float_as_uint(sel);
    unsigned int mapped = (sb >> 31) ? ~sb : (sb | 0x80000000u);  // sortable
    s_key[n] = ((unsigned long long)(~mapped) << 32) | (unsigned)n;
  }
  __syncthreads();

  int r = (b < K_OUT) ? b : b - K_OUT;
  for (int n = t; n < N_PROP; n += 256) {
    unsigned long long kn = s_key[n];
    int cnt = 0;
#pragma unroll 8
    for (int q = 0; q < N_PROP; ++q) cnt += (s_key[q] < kn) ? 1 : 0;
    if (cnt == r) s_win = n;  // exactly one writer (keys distinct)
  }
  __syncthreads();

  int n = s_win;
  float v = s_score[n];
  bool valid = v > 0.0f;
  float mm = valid ? 1.0f : 0.0f;
  int glab = valid ? (int)(0xFFFFFFFFu - s_low[n]) : 0;  // guard OOB when invalid

  if (b < K_OUT) {
    if (t == 0) {
      out[OF_SC + b] = valid ? v : 0.0f;
      out[OF_LB + b] = (float)glab;
      out[OF_VD + b] = mm;
      float4 pb = *(const float4*)(pboxes + n * 4);
      float4 bx = decode_box(pb, breg + ((size_t)n * NUM_CLS + glab) * 4);
      out[OF_BOX + b * 4 + 0] = bx.x * mm;
      out[OF_BOX + b * 4 + 1] = bx.y * mm;
      out[OF_BOX + b * 4 + 2] = bx.z * mm;
      out[OF_BOX + b * 4 + 3] = bx.w * mm;
    }
    const float4* src = (const float4*)(features + (size_t)n * FEAT_DIM);
    float4* dst = (float4*)(out + (size_t)b * FEAT_DIM);
    for (int i = t; i < FEAT_DIM / 4; i += 256) {
      float4 f = src[i];
      dst[i] = make_float4(f.x * mm, f.y * mm, f.z * mm, f.w * mm);
    }
  } else {
    int k = b - K_OUT;
    float4 pb = *(const float4*)(pboxes + n * 4);
    float4* dst = (float4*)(out + OF_BPC + (size_t)k * NUM_CLS * 4);
    for (int c = t; c < NUM_CLS; c += 256) {
      float4 bx = decode_box(pb, breg + ((size_t)n * NUM_CLS + c) * 4);
      dst[c] = make_float4(bx.x * mm, bx.y * mm, bx.z * mm, bx.w * mm);
    }
  }
}

extern "C" void kernel_launch(void* const* d_in, const int* in_sizes, int n_in,
                              void* d_out, int out_size, void* d_ws, size_t ws_size,
                              hipStream_t stream) {
  const float* features = (const float*)d_in[0];
  const float* logits   = (const float*)d_in[1];
  const float* breg     = (const float*)d_in[2];
  const float* pboxes   = (const float*)d_in[3];
  float* out = (float*)d_out;

  unsigned long long* packed = (unsigned long long*)d_ws;  // 600 u64

  hipMemsetAsync(packed, 0, N_PROP * sizeof(unsigned long long), stream);
  hipLaunchKernelGGL(nms_kernel, dim3(NUM_CLS - 1), dim3(256), 0, stream,
                     logits, breg, pboxes, packed);
  hipLaunchKernelGGL(finalize_gather_kernel, dim3(2 * K_OUT), dim3(256), 0,
                     stream, features, breg, pboxes, packed, out);
}